// Round 17
// baseline (73.579 us; speedup 1.0000x reference)
//
#include <hip/hip_runtime.h>

// One-way Chamfer (L1, K=1): out[0] = mean_i min_j ||x_i - y_j||_1 ; out[1..N] = 0
// N = M = 16384, D = 3, fp32.
//
// R17 = R16 with the compile fix: s_load needs an SGPR address; pointers
// derived from loads/shfl/threadIdx are divergent in LLVM's analysis even
// when runtime-uniform per wave. upf() readfirstlanes the pointer halves
// into SGPRs; rfl() uniformizes slice bounds so the trip count is scalar.
// Design (R16): sort both clouds by x into 1024 fixed slabs; bound kernel
// scans 512 rank-near pts per query-wave via the R10 s_load dbuf broadcast
// -> m(q), group mmax; window kernel scans the exact window
// [qxmin-mmax, qxmax+mmax] (+-1 slab slack) in 16 slices, same broadcast;
// combine via uint atomicMin. Window contains each member's L1 ball ->
// qmin == d_true exactly, independent of scatter permutation.

#define NB   1024
#define LOX  (-64.0f)
#define INVW 8.0f
#define NPAD 16

typedef float sf16 __attribute__((ext_vector_type(16)));
typedef float sf8  __attribute__((ext_vector_type(8)));

__device__ __forceinline__ int rfl(int v) {
    return __builtin_amdgcn_readfirstlane(v);
}
__device__ __forceinline__ const float* upf(const float* p) {
    union { const float* p; unsigned u[2]; } a;
    a.p = p;
    a.u[0] = (unsigned)__builtin_amdgcn_readfirstlane((int)a.u[0]);
    a.u[1] = (unsigned)__builtin_amdgcn_readfirstlane((int)a.u[1]);
    return a.p;
}

#define SLOAD24(B16, B8, PTR, O16, O8)                                     \
  asm volatile("s_load_dwordx16 %0, %2, " O16 "\n\t"                       \
               "s_load_dwordx8  %1, %2, " O8                               \
               : "=s"(B16), "=s"(B8) : "s"(PTR));

#define SWAIT(B16, B8)                                                     \
  asm volatile("s_waitcnt lgkmcnt(0)" : "+s"(B16), "+s"(B8));

// MR = min3(MR, |a-y0|_1, |a-y1|_1); y comps are SGPRs; 11 VALU / 2 pairs
#define DIST2S(MR, AXv, AYv, AZv, Y0X, Y0Y, Y0Z, Y1X, Y1Y, Y1Z)           \
  {                                                                        \
    float t0, t1, t2, t3, t4;                                              \
    asm("v_sub_f32 %1, %9, %6\n\t"                                         \
        "v_sub_f32 %2, %10, %7\n\t"                                        \
        "v_sub_f32 %3, %11, %8\n\t"                                        \
        "v_sub_f32 %4, %12, %6\n\t"                                        \
        "v_sub_f32 %5, %13, %7\n\t"                                        \
        "v_add_f32 %1, |%1|, |%2|\n\t"                                     \
        "v_sub_f32 %2, %14, %8\n\t"                                        \
        "v_add_f32 %4, |%4|, |%5|\n\t"                                     \
        "v_add_f32 %1, %1, |%3|\n\t"                                       \
        "v_add_f32 %4, %4, |%2|\n\t"                                       \
        "v_min3_f32 %0, %0, %1, %4"                                        \
        : "+v"(MR), "=&v"(t0), "=&v"(t1), "=&v"(t2), "=&v"(t3), "=&v"(t4)  \
        : "v"(AXv), "v"(AYv), "v"(AZv),                                    \
          "s"(Y0X), "s"(Y0Y), "s"(Y0Z), "s"(Y1X), "s"(Y1Y), "s"(Y1Z));    \
  }

#define COMPUTE8_1(G16, G8)                                                \
  {                                                                        \
    DIST2S(m, qx, qy, qz, G16[0], G16[1], G16[2], G16[3], G16[4], G16[5]); \
    DIST2S(m, qx, qy, qz, G16[6], G16[7], G16[8], G16[9], G16[10], G16[11]);\
    DIST2S(m, qx, qy, qz, G16[12], G16[13], G16[14], G16[15], G8[0], G8[1]);\
    DIST2S(m, qx, qy, qz, G8[2], G8[3], G8[4], G8[5], G8[6], G8[7]);       \
  }

__device__ __forceinline__ int slab_of(float x) {
    int b = (int)((x - LOX) * INVW);
    return (b < 0) ? 0 : ((b > NB - 1) ? NB - 1 : b);
}

__global__ __launch_bounds__(256) void hist_kernel(
    const float* __restrict__ pc1, const float* __restrict__ flow,
    const float* __restrict__ pc2, int* __restrict__ hist2,
    int* __restrict__ histq, int N, int M) {
    const int i = blockIdx.x * 256 + threadIdx.x;
    const int stride = gridDim.x * 256;
    for (int j = i; j < M; j += stride)
        atomicAdd(&hist2[slab_of(pc2[3 * j])], 1);
    for (int j = i; j < N; j += stride)
        atomicAdd(&histq[slab_of(pc1[3 * j] + flow[3 * j])], 1);
}

// 2 blocks: block 0 scans hist2 -> base2/cursor2 (+ base2[NB]); block 1 -> cursorq
__global__ __launch_bounds__(NB) void scan_kernel(
    const int* __restrict__ hist2, const int* __restrict__ histq,
    int* __restrict__ base2, int* __restrict__ cursor2, int* __restrict__ cursorq) {
    __shared__ int sc[NB];
    const int t = threadIdx.x;
    const int* h = (blockIdx.x == 0) ? hist2 : histq;
    const int hv = h[t];
    sc[t] = hv;
    __syncthreads();
    for (int off = 1; off < NB; off <<= 1) {
        int v = (t >= off) ? sc[t - off] : 0;
        __syncthreads();
        sc[t] += v;
        __syncthreads();
    }
    const int ex = sc[t] - hv;
    if (blockIdx.x == 0) {
        base2[t] = ex; cursor2[t] = ex;
        if (t == NB - 1) base2[NB] = sc[t];
    } else {
        cursorq[t] = ex;
    }
}

__global__ __launch_bounds__(256) void scatter_kernel(
    const float* __restrict__ pc1, const float* __restrict__ flow,
    const float* __restrict__ pc2, int* __restrict__ cursor2,
    int* __restrict__ cursorq, float* __restrict__ pts2,
    float4* __restrict__ qs, int N, int M) {
    const int i = blockIdx.x * 256 + threadIdx.x;
    const int stride = gridDim.x * 256;
    for (int j = i; j < M; j += stride) {
        const float x = pc2[3 * j], y = pc2[3 * j + 1], z = pc2[3 * j + 2];
        const int pos = atomicAdd(&cursor2[slab_of(x)], 1);
        pts2[3 * pos] = x; pts2[3 * pos + 1] = y; pts2[3 * pos + 2] = z;
    }
    for (int j = i; j < N; j += stride) {
        const float x = pc1[3 * j] + flow[3 * j];
        const float y = pc1[3 * j + 1] + flow[3 * j + 1];
        const float z = pc1[3 * j + 2] + flow[3 * j + 2];
        const int pos = atomicAdd(&cursorq[slab_of(x)], 1);
        qs[pos] = make_float4(x, y, z, __int_as_float(j));
    }
    // +inf pad: dbuf group overruns (<=15 pts) land here, never poison a min
    if (blockIdx.x == 0 && threadIdx.x < 3 * NPAD)
        pts2[3 * M + threadIdx.x] = 1.0e30f;
}

// group g = 64 rank-consecutive queries; scan 512 rank-near pc2 pts ->
// qmin init + mmax[g]. 4 waves each take 128 pts for the same 64 queries.
__global__ __launch_bounds__(256) void bound_kernel(
    const float4* __restrict__ qs, const float* __restrict__ pts2,
    const int* __restrict__ base2, float* __restrict__ mmaxArr,
    float* __restrict__ qmin, int N, int M) {
    const int t = threadIdx.x, w = t >> 6, l = t & 63, g = blockIdx.x;
    int qi = g * 64 + l; if (qi >= N) qi = N - 1;
    const float4 qf = qs[qi];
    const float qx = qf.x, qy = qf.y, qz = qf.z;

    const float qxm = __shfl(qx, 32, 64);
    const int c = base2[slab_of(qxm)];
    int ys = c - 224; ys = (ys < 0) ? 0 : ((ys > M - 512) ? M - 512 : ys);
    ys = rfl(ys);

    float m = 3.0e38f;
    {
        const float* yp = upf(pts2 + 3 * (ys + w * 128));
        sf16 A16, B16; sf8 A8, B8;
        SLOAD24(A16, A8, yp, "0", "64");
#pragma unroll 1
        for (int it = 0; it < 8; ++it) {          // 16 groups = 128 pts
            SWAIT(A16, A8);
            SLOAD24(B16, B8, yp, "96", "160");
            COMPUTE8_1(A16, A8);
            SWAIT(B16, B8);
            if (it + 1 < 8) SLOAD24(A16, A8, yp, "192", "256");
            COMPUTE8_1(B16, B8);
            yp += 48;
        }
    }
    __shared__ float smem[4][64];
    smem[w][l] = m;
    __syncthreads();
    if (t < 64) {
        float m4 = fminf(fminf(smem[0][t], smem[1][t]),
                         fminf(smem[2][t], smem[3][t]));
        qmin[__float_as_int(qf.w)] = m4;          // init (improved by window)
        float mm = m4;
#pragma unroll
        for (int off = 1; off < 64; off <<= 1)
            mm = fmaxf(mm, __shfl_xor(mm, off, 64));
        if (t == 0) mmaxArr[g] = mm;
    }
}

// 4 sub-blocks per group; window sliced 16 ways (4 sub x 4 waves)
__global__ __launch_bounds__(256) void window_kernel(
    const float4* __restrict__ qs, const float* __restrict__ pts2,
    const int* __restrict__ base2, const float* __restrict__ mmaxArr,
    unsigned* __restrict__ qmin, int N, int M) {
    const int t = threadIdx.x, w = t >> 6, l = t & 63;
    const int g = blockIdx.x >> 2, s = blockIdx.x & 3;
    int qi = g * 64 + l; if (qi >= N) qi = N - 1;
    const float4 qf = qs[qi];
    const float qx = qf.x, qy = qf.y, qz = qf.z;

    const float qx0 = __shfl(qx, 0, 64), qx1 = __shfl(qx, 63, 64);
    const float mm = mmaxArr[g];
    int bl = (int)((qx0 - mm - LOX) * INVW) - 1;   // -1: trunc-vs-floor + slack
    bl = (bl < 0) ? 0 : ((bl > NB - 1) ? NB - 1 : bl);
    int br = (int)((qx1 + mm - LOX) * INVW) + 1;
    br = (br < 0) ? 0 : ((br > NB - 1) ? NB - 1 : br);
    const int B = base2[bl], E = base2[br + 1];
    const int len = E - B;
    const int k = s * 4 + w;
    const int j0 = rfl(B + ((len * k) >> 4));
    const int j1 = rfl(B + ((len * (k + 1)) >> 4));
    const int n = j1 - j0;

    float m = 3.0e38f;
    if (n > 0) {
        const int NIT = ((((n + 7) >> 3) + 1) & ~1) >> 1;  // groups of 8, even
        const float* yp = upf(pts2 + 3 * j0);
        sf16 A16, B16; sf8 A8, B8;
        SLOAD24(A16, A8, yp, "0", "64");
#pragma unroll 1
        for (int it = 0; it < NIT; ++it) {
            SWAIT(A16, A8);
            SLOAD24(B16, B8, yp, "96", "160");
            COMPUTE8_1(A16, A8);
            SWAIT(B16, B8);
            if (it + 1 < NIT) SLOAD24(A16, A8, yp, "192", "256");
            COMPUTE8_1(B16, B8);
            yp += 48;
        }
    }
    __shared__ float smem[4][64];
    smem[w][l] = m;
    __syncthreads();
    if (t < 64) {
        const float m4 = fminf(fminf(smem[0][t], smem[1][t]),
                               fminf(smem[2][t], smem[3][t]));
        // exact order-independent combine (nonneg floats)
        atomicMin(&qmin[__float_as_int(qf.w)], __float_as_uint(m4));
    }
}

__global__ __launch_bounds__(1024) void final_kernel(
    const unsigned* __restrict__ qmin, float* __restrict__ out,
    int N, int out_size, float invN) {
    const int t = threadIdx.x;
    for (int kk = t; 1 + kk < out_size; kk += 1024) out[1 + kk] = 0.0f;
    float sacc = 0.0f;
    const uint4* p4 = (const uint4*)qmin;
    for (int kk = t; kk < N / 4; kk += 1024) {
        const uint4 v = p4[kk];
        sacc += __uint_as_float(v.x) + __uint_as_float(v.y) +
                __uint_as_float(v.z) + __uint_as_float(v.w);
    }
    for (int kk = (N / 4) * 4 + t; kk < N; kk += 1024)
        sacc += __uint_as_float(qmin[kk]);
#pragma unroll
    for (int off = 32; off; off >>= 1) sacc += __shfl_down(sacc, off, 64);
    __shared__ float ls[16];
    if ((t & 63) == 0) ls[t >> 6] = sacc;
    __syncthreads();
    if (t == 0) {
        float tot = 0.0f;
        for (int w2 = 0; w2 < 16; ++w2) tot += ls[w2];
        out[0] = tot * invN;
    }
}

extern "C" void kernel_launch(void* const* d_in, const int* in_sizes, int n_in,
                              void* d_out, int out_size, void* d_ws, size_t ws_size,
                              hipStream_t stream) {
    const float* pc1  = (const float*)d_in[0];
    const float* flow = (const float*)d_in[1];
    const float* pc2  = (const float*)d_in[2];
    float* out = (float*)d_out;

    const int N = in_sizes[0] / 3;
    const int M = in_sizes[2] / 3;

    char* ws = (char*)d_ws;
    int*    hist2   = (int*)(ws + 0);           // 4096
    int*    histq   = (int*)(ws + 4096);        // 4096
    int*    base2   = (int*)(ws + 8192);        // (NB+1)*4
    int*    cursor2 = (int*)(ws + 16384);       // 4096
    int*    cursorq = (int*)(ws + 20480);       // 4096
    float*  mmaxArr = (float*)(ws + 24576);     // NG*4
    float*  qmin    = (float*)(ws + 28672);     // N*4
    float*  pts2    = (float*)(ws + 94208);     // 3*M*4 + pad
    float4* qs      = (float4*)(ws + 291328);   // N*16

    const int NG = (N + 63) / 64;               // 256

    hipMemsetAsync(hist2, 0, 2 * NB * sizeof(int), stream);
    hist_kernel<<<64, 256, 0, stream>>>(pc1, flow, pc2, hist2, histq, N, M);
    scan_kernel<<<2, NB, 0, stream>>>(hist2, histq, base2, cursor2, cursorq);
    scatter_kernel<<<64, 256, 0, stream>>>(pc1, flow, pc2, cursor2, cursorq,
                                           pts2, qs, N, M);
    bound_kernel<<<NG, 256, 0, stream>>>(qs, pts2, base2, mmaxArr, qmin, N, M);
    window_kernel<<<NG * 4, 256, 0, stream>>>(qs, pts2, base2, mmaxArr,
                                              (unsigned*)qmin, N, M);
    final_kernel<<<1, 1024, 0, stream>>>((const unsigned*)qmin, out, N,
                                         out_size, 1.0f / (float)N);
}